// Round 8
// baseline (310.717 us; speedup 1.0000x reference)
//
#include <hip/hip_runtime.h>
#include <hip/hip_bf16.h>
#include <stdint.h>

typedef __bf16 bf16;
typedef __bf16 bf16x8 __attribute__((ext_vector_type(8)));
typedef float f32x4 __attribute__((ext_vector_type(4)));

#define BB   2048
#define ISZ  512
#define NN   2048
#define OSZ  128

// ---------------------------------------------------------------------------
// Fused prep: 4 pack regions (fp32 -> bf16, 8 elems/thread) + 7 transposes
// ---------------------------------------------------------------------------
struct PackD { const float* src; bf16* dst; int W, ld, off, n8; };
struct TD    { const float* src; const float* msk; bf16* dst;
               int Ncols, ld_dst, k_off, mode, ntx, start; };
struct PAll  { PackD p[4]; TD d[7]; int packBlocks; };

__global__ __launch_bounds__(256) void prep_all_k(PAll a) {
  if ((int)blockIdx.x < a.packBlocks) {
    int idx = blockIdx.x * 256 + threadIdx.x;
    PackD d = a.p[0]; int base = 0;
#pragma unroll
    for (int i = 1; i < 4; ++i) if (idx >= a.p[i - 1].n8) { d = a.p[i]; base = a.p[i - 1].n8; }
    if (idx >= d.n8) return;
    int e = (idx - base) * 8;
    int m = e / d.W;
    int c = e - m * d.W;
    const float4 v0 = *reinterpret_cast<const float4*>(d.src + e);
    const float4 v1 = *reinterpret_cast<const float4*>(d.src + e + 4);
    bf16x8 o;
    o[0] = (bf16)v0.x; o[1] = (bf16)v0.y; o[2] = (bf16)v0.z; o[3] = (bf16)v0.w;
    o[4] = (bf16)v1.x; o[5] = (bf16)v1.y; o[6] = (bf16)v1.z; o[7] = (bf16)v1.w;
    *reinterpret_cast<bf16x8*>(d.dst + (size_t)m * d.ld + d.off + c) = o;
    return;
  }
  int bid = blockIdx.x - a.packBlocks;
  TD d = a.d[0];
#pragma unroll
  for (int i = 1; i < 7; ++i) if (bid >= a.d[i].start) d = a.d[i];
  int local = bid - d.start;
  int k0 = (local % d.ntx) * 32;
  int n0 = (local / d.ntx) * 32;
  __shared__ float t[32][33];
  const int tx = threadIdx.x & 31, ty = threadIdx.x >> 5;
#pragma unroll
  for (int i = 0; i < 4; ++i) {
    int k = k0 + ty + i * 8;
    float v = d.src[(size_t)k * d.Ncols + n0 + tx];
    if (d.mode == 1 && k == (n0 + tx)) v = 0.f;
    if (d.mode == 2) v *= d.msk[(size_t)k * d.Ncols + n0 + tx];
    t[ty + i * 8][tx] = v;
  }
  __syncthreads();
#pragma unroll
  for (int i = 0; i < 4; ++i) {
    int n = n0 + ty + i * 8;
    d.dst[(size_t)n * d.ld_dst + d.k_off + k0 + tx] = (bf16)t[tx][ty + i * 8];
  }
}

// ---------------------------------------------------------------------------
// GEMM descriptor; epi 0: pre = acc + bias[col] (+ radd);
// h = hin*0.9 + relu(pre)*0.1 -> fp32 outf + bf16 nxt.   epi 1: fp32 acc.
// ---------------------------------------------------------------------------
struct GP {
  const bf16* A; const bf16* B;
  int K, lda, ldb;
  const float* hin; const float* bias; const float* radd;
  float* outf; int ld_out;
  bf16* nxt; int ld_nxt;
  int epi;
};

__device__ __forceinline__ void gload16(const bf16* g, bf16* l) {
  __builtin_amdgcn_global_load_lds(
      (const __attribute__((address_space(1))) void*)g,
      (__attribute__((address_space(3))) void*)l, 16, 0, 0);
}

__device__ __forceinline__ void epilogue_store(const GP& p, int row, int col, float v) {
  size_t oidx = (size_t)row * p.ld_out + col;
  if (p.epi == 0) {
    float pre = v + p.bias[col];
    if (p.radd) pre += p.radd[oidx];
    float h = p.hin[oidx] * 0.9f + fmaxf(pre, 0.f) * 0.1f;
    p.outf[oidx] = h;
    p.nxt[(size_t)row * p.ld_nxt + col] = (bf16)h;
  } else {
    p.outf[oidx] = v;
  }
}

// ---------------------------------------------------------------------------
// R3-verified structure: 8 waves (2Mx4N, wave-tile 64x32), BK=32, double-
// buffered LDS, 2-phase syncthreads loop, XCD swizzle.
// R8 change: staging lane map = (lane&15, (lane>>4)*8) so LDS chunk c holds
// lane l's MFMA fragment at byte offset l*16 -> fragment reads are fully
// lane-linear ds_read_b128 (zero bank conflicts). Identity: (l>>4)*16+(l&15)=l.
// ---------------------------------------------------------------------------
template<int BM, int BN>
__device__ __forceinline__ void gemm_body8(const GP p) {
  constexpr int BK = 32;
  constexpr int WM = BM / 2, WN = BN / 4;      // 2x4 wave grid
  constexpr int FM = WM / 16, FN = WN / 16;
  __shared__ bf16 As[2][BM][BK];
  __shared__ bf16 Bs[2][BN][BK];
  const int tid  = threadIdx.x;
  const int lane = tid & 63;
  const int wave = tid >> 6;                   // 0..7
  // XCD-aware swizzle (all grids have nwg % 8 == 0 per z-slice)
  const int gx = gridDim.x, nwg = gx * gridDim.y;
  const int lid = blockIdx.x + gx * blockIdx.y;
  const int q = nwg >> 3;
  const int swz = (lid & 7) * q + (lid >> 3);
  const int m0 = (swz / gx) * BM, n0 = (swz % gx) * BN;
  const int wm0 = (wave >> 2) * WM, wn0 = (wave & 3) * WN;
  const int srow = lane & 15;                  // staging row within 16-row chunk
  const int scolE = (lane >> 4) * 8;           // staging col (elems) within BK
  f32x4 acc[FM][FN];
#pragma unroll
  for (int i = 0; i < FM; ++i)
#pragma unroll
    for (int j = 0; j < FN; ++j)
#pragma unroll
      for (int r = 0; r < 4; ++r) acc[i][j][r] = 0.f;

  auto stage = [&](int buf, int t) {
    const int k0 = t * BK;
#pragma unroll
    for (int c = wave; c < BM / 16; c += 8) {
      const bf16* g = p.A + (size_t)(m0 + c * 16 + srow) * p.lda + k0 + scolE;
      gload16(g, &As[buf][0][0] + c * 512);
    }
#pragma unroll
    for (int c = wave; c < BN / 16; c += 8) {
      const bf16* g = p.B + (size_t)(n0 + c * 16 + srow) * p.ldb + k0 + scolE;
      gload16(g, &Bs[buf][0][0] + c * 512);
    }
  };

  const int nt = p.K / BK;
  stage(0, 0);
  __syncthreads();
  int cur = 0;
  for (int t = 0; t < nt; ++t) {
    if (t + 1 < nt) stage(cur ^ 1, t + 1);     // next tile's loads in flight
    bf16x8 af[FM], bfrag[FN];
#pragma unroll
    for (int i = 0; i < FM; ++i)
      af[i] = *reinterpret_cast<const bf16x8*>(&As[cur][wm0 + i * 16][0] + lane * 8);
#pragma unroll
    for (int j = 0; j < FN; ++j)
      bfrag[j] = *reinterpret_cast<const bf16x8*>(&Bs[cur][wn0 + j * 16][0] + lane * 8);
#pragma unroll
    for (int i = 0; i < FM; ++i)
#pragma unroll
      for (int j = 0; j < FN; ++j)
        acc[i][j] = __builtin_amdgcn_mfma_f32_16x16x32_bf16(af[i], bfrag[j], acc[i][j], 0, 0, 0);
    __syncthreads();                           // drains stage's vmcnt + reuse fence
    cur ^= 1;
  }

  // epilogue: C/D layout col = lane&15, row = (lane>>4)*4 + reg
#pragma unroll
  for (int i = 0; i < FM; ++i)
#pragma unroll
    for (int j = 0; j < FN; ++j)
#pragma unroll
      for (int r = 0; r < 4; ++r)
        epilogue_store(p, m0 + wm0 + i * 16 + (lane >> 4) * 4 + r,
                       n0 + wn0 + j * 16 + (lane & 15), acc[i][j][r]);
}

__global__ __launch_bounds__(512) void k_tri(GP p0, GP p1, GP p2) {
  GP p;
  if (blockIdx.z == 0) p = p0;
  else if (blockIdx.z == 1) p = p1;
  else p = p2;
  gemm_body8<128, 128>(p);
}

__global__ __launch_bounds__(512) void k_split(GP p0, GP p1) {
  gemm_body8<128, 128>(blockIdx.z == 0 ? p0 : p1);
}

__global__ __launch_bounds__(512) void k_out(GP p) { gemm_body8<32, 64>(p); }

// elementwise: h = hin*0.9 + relu(P0+P1+radd+bias)*0.1 -> fp32 out + bf16 nxt
__global__ __launch_bounds__(256) void k_epi(const float* __restrict__ P0,
                                             const float* __restrict__ P1,
                                             const float* __restrict__ radd,
                                             const float* __restrict__ hin,
                                             const float* __restrict__ bias,
                                             float* __restrict__ outf,
                                             bf16* __restrict__ nxt) {
  int e = (blockIdx.x * 256 + threadIdx.x) * 8;
  int colb = e & (NN - 1);
  const float4 a0 = *reinterpret_cast<const float4*>(P0 + e);
  const float4 a1 = *reinterpret_cast<const float4*>(P0 + e + 4);
  const float4 b0 = *reinterpret_cast<const float4*>(P1 + e);
  const float4 b1 = *reinterpret_cast<const float4*>(P1 + e + 4);
  const float4 r0 = *reinterpret_cast<const float4*>(radd + e);
  const float4 r1 = *reinterpret_cast<const float4*>(radd + e + 4);
  const float4 h0 = *reinterpret_cast<const float4*>(hin + e);
  const float4 h1 = *reinterpret_cast<const float4*>(hin + e + 4);
  const float4 c0 = *reinterpret_cast<const float4*>(bias + colb);
  const float4 c1 = *reinterpret_cast<const float4*>(bias + colb + 4);
  float pa[8] = {a0.x, a0.y, a0.z, a0.w, a1.x, a1.y, a1.z, a1.w};
  float pb[8] = {b0.x, b0.y, b0.z, b0.w, b1.x, b1.y, b1.z, b1.w};
  float pr[8] = {r0.x, r0.y, r0.z, r0.w, r1.x, r1.y, r1.z, r1.w};
  float ph[8] = {h0.x, h0.y, h0.z, h0.w, h1.x, h1.y, h1.z, h1.w};
  float pc[8] = {c0.x, c0.y, c0.z, c0.w, c1.x, c1.y, c1.z, c1.w};
  float4 o0, o1;
  bf16x8 nb;
#pragma unroll
  for (int j = 0; j < 8; ++j) {
    float pre = pa[j] + pb[j] + pr[j] + pc[j];
    float h = ph[j] * 0.9f + fmaxf(pre, 0.f) * 0.1f;
    (j < 4 ? (&o0.x)[j] : (&o1.x)[j - 4]) = h;
    nb[j] = (bf16)h;
  }
  *reinterpret_cast<float4*>(outf + e) = o0;
  *reinterpret_cast<float4*>(outf + e + 4) = o1;
  *reinterpret_cast<bf16x8*>(nxt + e) = nb;
}

// ---------------------------------------------------------------------------
extern "C" void kernel_launch(void* const* d_in, const int* in_sizes, int n_in,
                              void* d_out, int out_size, void* d_ws, size_t ws_size,
                              hipStream_t stream) {
  const float* x        = (const float*)d_in[0];
  const float* h0_in    = (const float*)d_in[1];
  const float* h1_in    = (const float*)d_in[2];
  const float* h2_in    = (const float*)d_in[3];
  const float* i_to_h0  = (const float*)d_in[4];
  const float* h0_w     = (const float*)d_in[5];
  const float* h0_b     = (const float*)d_in[6];
  const float* h0_to_h1 = (const float*)d_in[7];
  const float* h1_w     = (const float*)d_in[8];
  const float* h1_b     = (const float*)d_in[9];
  const float* h1_to_h2 = (const float*)d_in[10];
  const float* h2_w     = (const float*)d_in[11];
  const float* h2_b     = (const float*)d_in[12];
  const float* w_out    = (const float*)d_in[13];
  const float* m01      = (const float*)d_in[14];
  const float* m12      = (const float*)d_in[15];
  float* out = (float*)d_out;

  uint8_t* ws = (uint8_t*)d_ws;
  constexpr size_t OFF_A0  = 0;                    // [2048][2560] A of S0
  constexpr size_t OFF_W0  = OFF_A0 + 10485760;    // [2048][2560] B^T of S0
  constexpr size_t OFF_W1R = OFF_W0 + 10485760;    // [2048][2048] h1_w'^T
  constexpr size_t OFF_W2R = OFF_W1R + 8388608;    // [2048][2048] h2_w'^T
  constexpr size_t OFF_W01 = OFF_W2R + 8388608;    // [2048][2048] h01m^T
  constexpr size_t OFF_W12 = OFF_W01 + 8388608;    // [2048][2048] h12m^T
  constexpr size_t OFF_WO  = OFF_W12 + 8388608;    // [128][2048]  w_out^T
  constexpr size_t OFF_AR1 = OFF_WO + 524288;      // h1_in bf16 -> later h1 bf16
  constexpr size_t OFF_AR2 = OFF_AR1 + 8388608;    // h2_in bf16 -> later h2 bf16
  constexpr size_t OFF_AH0 = OFF_AR2 + 8388608;    // h0 bf16
  constexpr size_t WS_NEED = OFF_AH0 + 8388608;    // ~80.2 MB
  if (ws_size < WS_NEED) return;

  bf16* A0  = (bf16*)(ws + OFF_A0);
  bf16* Wt0 = (bf16*)(ws + OFF_W0);
  bf16* W1r = (bf16*)(ws + OFF_W1R);
  bf16* W2r = (bf16*)(ws + OFF_W2R);
  bf16* W01 = (bf16*)(ws + OFF_W01);
  bf16* W12 = (bf16*)(ws + OFF_W12);
  bf16* WtO = (bf16*)(ws + OFF_WO);
  bf16* Ar1 = (bf16*)(ws + OFF_AR1);
  bf16* Ar2 = (bf16*)(ws + OFF_AR2);
  bf16* Ah0 = (bf16*)(ws + OFF_AH0);
  bf16* Ah1 = Ar1;   // h1_in bf16 dead after D1
  bf16* Ah2 = Ar2;   // h2_in bf16 dead after D1
  // split-K partials in regions dead after D1 (A0/Wt0/W1r/W2r): 32 MB used,
  // ends at 33.6 MB < OFF_W01 (37.7 MB) -> W01/W12 untouched.
  float* P0 = (float*)(ws + 0);
  float* P1 = (float*)(ws + 16777216);

  float* o_h0  = out;
  float* o_h1  = out + (size_t)BB * NN;
  float* o_h2  = out + (size_t)2 * BB * NN;
  float* o_out = out + (size_t)3 * BB * NN;

  // --- fused prep (1 dispatch) ---
  PAll pa;
  int n8a = BB * ISZ / 8;
  int n8b = n8a + BB * NN / 8;
  int n8c = n8b + BB * NN / 8;
  int n8d = n8c + BB * NN / 8;
  pa.p[0] = {x,     A0,  ISZ, ISZ + NN, 0,   n8a};
  pa.p[1] = {h0_in, A0,  NN,  ISZ + NN, ISZ, n8b};
  pa.p[2] = {h1_in, Ar1, NN,  NN,       0,   n8c};
  pa.p[3] = {h2_in, Ar2, NN,  NN,       0,   n8d};
  pa.packBlocks = (n8d + 255) / 256;
  int s0 = 0;
  pa.d[0] = {i_to_h0,  nullptr, Wt0, NN,  ISZ + NN, 0,   0, ISZ / 32, s0}; s0 += (ISZ / 32) * (NN / 32);
  pa.d[1] = {h0_w,     nullptr, Wt0, NN,  ISZ + NN, ISZ, 1, NN / 32,  s0}; s0 += (NN / 32) * (NN / 32);
  pa.d[2] = {h1_w,     nullptr, W1r, NN,  NN,       0,   1, NN / 32,  s0}; s0 += (NN / 32) * (NN / 32);
  pa.d[3] = {h2_w,     nullptr, W2r, NN,  NN,       0,   1, NN / 32,  s0}; s0 += (NN / 32) * (NN / 32);
  pa.d[4] = {h0_to_h1, m01,     W01, NN,  NN,       0,   2, NN / 32,  s0}; s0 += (NN / 32) * (NN / 32);
  pa.d[5] = {h1_to_h2, m12,     W12, NN,  NN,       0,   2, NN / 32,  s0}; s0 += (NN / 32) * (NN / 32);
  pa.d[6] = {w_out,    nullptr, WtO, OSZ, NN,       0,   0, NN / 32,  s0}; s0 += (NN / 32) * (OSZ / 32);
  prep_all_k<<<pa.packBlocks + s0, 256, 0, stream>>>(pa);

  // --- D1: S0 (h0) + R1 + R2, 768 blocks of 8 waves, 128x128 ---
  GP pS0{A0,  Wt0, ISZ + NN, ISZ + NN, ISZ + NN, h0_in, h0_b, nullptr,
         o_h0, NN, Ah0, NN, 0};
  GP pR1{Ar1, W1r, NN, NN, NN, nullptr, nullptr, nullptr, o_h1, NN, nullptr, 0, 1};
  GP pR2{Ar2, W2r, NN, NN, NN, nullptr, nullptr, nullptr, o_h2, NN, nullptr, 0, 1};
  k_tri<<<dim3(NN / 128, BB / 128, 3), 512, 0, stream>>>(pS0, pR1, pR2);

  // --- D2: F1 = h0@W01 split-K=2 (512 blocks); combine with R1 -> h1 ---
  GP pG1a{Ah0,          W01,          NN / 2, NN, NN, nullptr, nullptr, nullptr, P0, NN, nullptr, 0, 1};
  GP pG1b{Ah0 + NN / 2, W01 + NN / 2, NN / 2, NN, NN, nullptr, nullptr, nullptr, P1, NN, nullptr, 0, 1};
  k_split<<<dim3(NN / 128, BB / 128, 2), 512, 0, stream>>>(pG1a, pG1b);
  k_epi<<<BB * NN / 2048, 256, 0, stream>>>(P0, P1, o_h1, h1_in, h1_b, o_h1, Ah1);

  // --- D3: F2 = h1@W12 split-K=2; combine with R2 -> h2 ---
  GP pG2a{Ah1,          W12,          NN / 2, NN, NN, nullptr, nullptr, nullptr, P0, NN, nullptr, 0, 1};
  GP pG2b{Ah1 + NN / 2, W12 + NN / 2, NN / 2, NN, NN, nullptr, nullptr, nullptr, P1, NN, nullptr, 0, 1};
  k_split<<<dim3(NN / 128, BB / 128, 2), 512, 0, stream>>>(pG2a, pG2b);
  k_epi<<<BB * NN / 2048, 256, 0, stream>>>(P0, P1, o_h2, h2_in, h2_b, o_h2, Ah2);

  // --- D4: out = h2 @ w_out ---
  GP pO{Ah2, WtO, NN, NN, NN, nullptr, nullptr, nullptr, o_out, OSZ, nullptr, 0, 1};
  k_out<<<dim3(OSZ / 64, BB / 32), 512, 0, stream>>>(pO);
}

// Round 9
// 257.644 us; speedup vs baseline: 1.2060x; 1.2060x over previous
//
#include <hip/hip_runtime.h>
#include <hip/hip_bf16.h>
#include <stdint.h>

typedef __bf16 bf16;
typedef __bf16 bf16x8 __attribute__((ext_vector_type(8)));
typedef float f32x4 __attribute__((ext_vector_type(4)));

#define BB   2048
#define ISZ  512
#define NN   2048
#define OSZ  128

// ---------------------------------------------------------------------------
// Fused prep: 4 pack regions (fp32 -> bf16, 8 elems/thread) + 7 transposes
// ---------------------------------------------------------------------------
struct PackD { const float* src; bf16* dst; int W, ld, off, n8; };
struct TD    { const float* src; const float* msk; bf16* dst;
               int Ncols, ld_dst, k_off, mode, ntx, start; };
struct PAll  { PackD p[4]; TD d[7]; int packBlocks; };

__global__ __launch_bounds__(256) void prep_all_k(PAll a) {
  if ((int)blockIdx.x < a.packBlocks) {
    int idx = blockIdx.x * 256 + threadIdx.x;
    PackD d = a.p[0]; int base = 0;
#pragma unroll
    for (int i = 1; i < 4; ++i) if (idx >= a.p[i - 1].n8) { d = a.p[i]; base = a.p[i - 1].n8; }
    if (idx >= d.n8) return;
    int e = (idx - base) * 8;
    int m = e / d.W;
    int c = e - m * d.W;
    const float4 v0 = *reinterpret_cast<const float4*>(d.src + e);
    const float4 v1 = *reinterpret_cast<const float4*>(d.src + e + 4);
    bf16x8 o;
    o[0] = (bf16)v0.x; o[1] = (bf16)v0.y; o[2] = (bf16)v0.z; o[3] = (bf16)v0.w;
    o[4] = (bf16)v1.x; o[5] = (bf16)v1.y; o[6] = (bf16)v1.z; o[7] = (bf16)v1.w;
    *reinterpret_cast<bf16x8*>(d.dst + (size_t)m * d.ld + d.off + c) = o;
    return;
  }
  int bid = blockIdx.x - a.packBlocks;
  TD d = a.d[0];
#pragma unroll
  for (int i = 1; i < 7; ++i) if (bid >= a.d[i].start) d = a.d[i];
  int local = bid - d.start;
  int k0 = (local % d.ntx) * 32;
  int n0 = (local / d.ntx) * 32;
  __shared__ float t[32][33];
  const int tx = threadIdx.x & 31, ty = threadIdx.x >> 5;
#pragma unroll
  for (int i = 0; i < 4; ++i) {
    int k = k0 + ty + i * 8;
    float v = d.src[(size_t)k * d.Ncols + n0 + tx];
    if (d.mode == 1 && k == (n0 + tx)) v = 0.f;
    if (d.mode == 2) v *= d.msk[(size_t)k * d.Ncols + n0 + tx];
    t[ty + i * 8][tx] = v;
  }
  __syncthreads();
#pragma unroll
  for (int i = 0; i < 4; ++i) {
    int n = n0 + ty + i * 8;
    d.dst[(size_t)n * d.ld_dst + d.k_off + k0 + tx] = (bf16)t[tx][ty + i * 8];
  }
}

// ---------------------------------------------------------------------------
// GEMM descriptor; epi 0: pre = acc + bias[col] (+ radd);
// h = hin*0.9 + relu(pre)*0.1 -> fp32 outf + bf16 nxt.   epi 1: fp32 acc.
// ---------------------------------------------------------------------------
struct GP {
  const bf16* A; const bf16* B;
  int K, lda, ldb;
  const float* hin; const float* bias; const float* radd;
  float* outf; int ld_out;
  bf16* nxt; int ld_nxt;
  int epi;
};

__device__ __forceinline__ void gload16(const bf16* g, bf16* l) {
  __builtin_amdgcn_global_load_lds(
      (const __attribute__((address_space(1))) void*)g,
      (__attribute__((address_space(3))) void*)l, 16, 0, 0);
}

__device__ __forceinline__ void epilogue_store(const GP& p, int row, int col, float v) {
  size_t oidx = (size_t)row * p.ld_out + col;
  if (p.epi == 0) {
    float pre = v + p.bias[col];
    if (p.radd) pre += p.radd[oidx];
    float h = p.hin[oidx] * 0.9f + fmaxf(pre, 0.f) * 0.1f;
    p.outf[oidx] = h;
    p.nxt[(size_t)row * p.ld_nxt + col] = (bf16)h;
  } else {
    p.outf[oidx] = v;
  }
}

// ---------------------------------------------------------------------------
// R3-verified structure: 8 waves (2Mx4N, wave-tile 64x32), BK=32, double-
// buffered LDS, 2-phase syncthreads loop, XCD swizzle.
// R9 change: k-slot XOR swizzle that keeps staging coalescing.
//   stage: lane l -> row l>>2 (4 consecutive lanes cover the row's 64B,
//          coalescing identical to R3/R7), col slot (l&3)^((l>>3)&3).
//   read:  k-slot K of row r lives at physical slot K^((r>>1)&3)
//          -> per 16-lane group, 8 distinct 16B slots mod 128B = 2-way
//          aliasing = free (was 8-way conflict in R3/R7).
// ---------------------------------------------------------------------------
template<int BM, int BN>
__device__ __forceinline__ void gemm_body8(const GP p) {
  constexpr int BK = 32;
  constexpr int WM = BM / 2, WN = BN / 4;      // 2x4 wave grid
  constexpr int FM = WM / 16, FN = WN / 16;
  __shared__ bf16 As[2][BM][BK];
  __shared__ bf16 Bs[2][BN][BK];
  const int tid  = threadIdx.x;
  const int lane = tid & 63;
  const int wave = tid >> 6;                   // 0..7
  // XCD-aware swizzle (all grids have nwg % 8 == 0 per z-slice)
  const int gx = gridDim.x, nwg = gx * gridDim.y;
  const int lid = blockIdx.x + gx * blockIdx.y;
  const int q = nwg >> 3;
  const int swz = (lid & 7) * q + (lid >> 3);
  const int m0 = (swz / gx) * BM, n0 = (swz % gx) * BN;
  const int wm0 = (wave >> 2) * WM, wn0 = (wave & 3) * WN;
  const int srow = lane >> 2;                              // staging row in chunk
  const int scolE = (((lane & 3) ^ ((lane >> 3) & 3)) * 8); // swizzled col slot
  const int frow = lane & 15;                              // fragment row
  const int rcolE = (((lane >> 4) ^ ((frow >> 1) & 3)) * 8); // swizzled read slot

  f32x4 acc[FM][FN];
#pragma unroll
  for (int i = 0; i < FM; ++i)
#pragma unroll
    for (int j = 0; j < FN; ++j)
#pragma unroll
      for (int r = 0; r < 4; ++r) acc[i][j][r] = 0.f;

  auto stage = [&](int buf, int t) {
    const int k0 = t * BK;
#pragma unroll
    for (int c = wave; c < BM / 16; c += 8) {
      const bf16* g = p.A + (size_t)(m0 + c * 16 + srow) * p.lda + k0 + scolE;
      gload16(g, &As[buf][0][0] + c * 512);
    }
#pragma unroll
    for (int c = wave; c < BN / 16; c += 8) {
      const bf16* g = p.B + (size_t)(n0 + c * 16 + srow) * p.ldb + k0 + scolE;
      gload16(g, &Bs[buf][0][0] + c * 512);
    }
  };

  const int nt = p.K / BK;
  stage(0, 0);
  __syncthreads();
  int cur = 0;
  for (int t = 0; t < nt; ++t) {
    if (t + 1 < nt) stage(cur ^ 1, t + 1);     // next tile's loads in flight
    bf16x8 af[FM], bfrag[FN];
#pragma unroll
    for (int i = 0; i < FM; ++i)
      af[i] = *reinterpret_cast<const bf16x8*>(&As[cur][wm0 + i * 16 + frow][rcolE]);
#pragma unroll
    for (int j = 0; j < FN; ++j)
      bfrag[j] = *reinterpret_cast<const bf16x8*>(&Bs[cur][wn0 + j * 16 + frow][rcolE]);
#pragma unroll
    for (int i = 0; i < FM; ++i)
#pragma unroll
      for (int j = 0; j < FN; ++j)
        acc[i][j] = __builtin_amdgcn_mfma_f32_16x16x32_bf16(af[i], bfrag[j], acc[i][j], 0, 0, 0);
    __syncthreads();                           // drains stage's vmcnt + reuse fence
    cur ^= 1;
  }

  // epilogue: C/D layout col = lane&15, row = (lane>>4)*4 + reg
#pragma unroll
  for (int i = 0; i < FM; ++i)
#pragma unroll
    for (int j = 0; j < FN; ++j)
#pragma unroll
      for (int r = 0; r < 4; ++r)
        epilogue_store(p, m0 + wm0 + i * 16 + (lane >> 4) * 4 + r,
                       n0 + wn0 + j * 16 + (lane & 15), acc[i][j][r]);
}

__global__ __launch_bounds__(512) void k_tri(GP p0, GP p1, GP p2) {
  GP p;
  if (blockIdx.z == 0) p = p0;
  else if (blockIdx.z == 1) p = p1;
  else p = p2;
  gemm_body8<128, 128>(p);
}

__global__ __launch_bounds__(512) void k_split(GP p0, GP p1) {
  gemm_body8<128, 128>(blockIdx.z == 0 ? p0 : p1);
}

__global__ __launch_bounds__(512) void k_out(GP p) { gemm_body8<32, 64>(p); }

// elementwise: h = hin*0.9 + relu(P0+P1+radd+bias)*0.1 -> fp32 out + bf16 nxt
__global__ __launch_bounds__(256) void k_epi(const float* __restrict__ P0,
                                             const float* __restrict__ P1,
                                             const float* __restrict__ radd,
                                             const float* __restrict__ hin,
                                             const float* __restrict__ bias,
                                             float* __restrict__ outf,
                                             bf16* __restrict__ nxt) {
  int e = (blockIdx.x * 256 + threadIdx.x) * 8;
  int colb = e & (NN - 1);
  const float4 a0 = *reinterpret_cast<const float4*>(P0 + e);
  const float4 a1 = *reinterpret_cast<const float4*>(P0 + e + 4);
  const float4 b0 = *reinterpret_cast<const float4*>(P1 + e);
  const float4 b1 = *reinterpret_cast<const float4*>(P1 + e + 4);
  const float4 r0 = *reinterpret_cast<const float4*>(radd + e);
  const float4 r1 = *reinterpret_cast<const float4*>(radd + e + 4);
  const float4 h0 = *reinterpret_cast<const float4*>(hin + e);
  const float4 h1 = *reinterpret_cast<const float4*>(hin + e + 4);
  const float4 c0 = *reinterpret_cast<const float4*>(bias + colb);
  const float4 c1 = *reinterpret_cast<const float4*>(bias + colb + 4);
  float pa[8] = {a0.x, a0.y, a0.z, a0.w, a1.x, a1.y, a1.z, a1.w};
  float pb[8] = {b0.x, b0.y, b0.z, b0.w, b1.x, b1.y, b1.z, b1.w};
  float pr[8] = {r0.x, r0.y, r0.z, r0.w, r1.x, r1.y, r1.z, r1.w};
  float ph[8] = {h0.x, h0.y, h0.z, h0.w, h1.x, h1.y, h1.z, h1.w};
  float pc[8] = {c0.x, c0.y, c0.z, c0.w, c1.x, c1.y, c1.z, c1.w};
  float4 o0, o1;
  bf16x8 nb;
#pragma unroll
  for (int j = 0; j < 8; ++j) {
    float pre = pa[j] + pb[j] + pr[j] + pc[j];
    float h = ph[j] * 0.9f + fmaxf(pre, 0.f) * 0.1f;
    (j < 4 ? (&o0.x)[j] : (&o1.x)[j - 4]) = h;
    nb[j] = (bf16)h;
  }
  *reinterpret_cast<float4*>(outf + e) = o0;
  *reinterpret_cast<float4*>(outf + e + 4) = o1;
  *reinterpret_cast<bf16x8*>(nxt + e) = nb;
}

// ---------------------------------------------------------------------------
extern "C" void kernel_launch(void* const* d_in, const int* in_sizes, int n_in,
                              void* d_out, int out_size, void* d_ws, size_t ws_size,
                              hipStream_t stream) {
  const float* x        = (const float*)d_in[0];
  const float* h0_in    = (const float*)d_in[1];
  const float* h1_in    = (const float*)d_in[2];
  const float* h2_in    = (const float*)d_in[3];
  const float* i_to_h0  = (const float*)d_in[4];
  const float* h0_w     = (const float*)d_in[5];
  const float* h0_b     = (const float*)d_in[6];
  const float* h0_to_h1 = (const float*)d_in[7];
  const float* h1_w     = (const float*)d_in[8];
  const float* h1_b     = (const float*)d_in[9];
  const float* h1_to_h2 = (const float*)d_in[10];
  const float* h2_w     = (const float*)d_in[11];
  const float* h2_b     = (const float*)d_in[12];
  const float* w_out    = (const float*)d_in[13];
  const float* m01      = (const float*)d_in[14];
  const float* m12      = (const float*)d_in[15];
  float* out = (float*)d_out;

  uint8_t* ws = (uint8_t*)d_ws;
  constexpr size_t OFF_A0  = 0;                    // [2048][2560] A of S0
  constexpr size_t OFF_W0  = OFF_A0 + 10485760;    // [2048][2560] B^T of S0
  constexpr size_t OFF_W1R = OFF_W0 + 10485760;    // [2048][2048] h1_w'^T
  constexpr size_t OFF_W2R = OFF_W1R + 8388608;    // [2048][2048] h2_w'^T
  constexpr size_t OFF_W01 = OFF_W2R + 8388608;    // [2048][2048] h01m^T
  constexpr size_t OFF_W12 = OFF_W01 + 8388608;    // [2048][2048] h12m^T
  constexpr size_t OFF_WO  = OFF_W12 + 8388608;    // [128][2048]  w_out^T
  constexpr size_t OFF_AR1 = OFF_WO + 524288;      // h1_in bf16 -> later h1 bf16
  constexpr size_t OFF_AR2 = OFF_AR1 + 8388608;    // h2_in bf16 -> later h2 bf16
  constexpr size_t OFF_AH0 = OFF_AR2 + 8388608;    // h0 bf16
  constexpr size_t WS_NEED = OFF_AH0 + 8388608;    // ~80.2 MB
  if (ws_size < WS_NEED) return;

  bf16* A0  = (bf16*)(ws + OFF_A0);
  bf16* Wt0 = (bf16*)(ws + OFF_W0);
  bf16* W1r = (bf16*)(ws + OFF_W1R);
  bf16* W2r = (bf16*)(ws + OFF_W2R);
  bf16* W01 = (bf16*)(ws + OFF_W01);
  bf16* W12 = (bf16*)(ws + OFF_W12);
  bf16* WtO = (bf16*)(ws + OFF_WO);
  bf16* Ar1 = (bf16*)(ws + OFF_AR1);
  bf16* Ar2 = (bf16*)(ws + OFF_AR2);
  bf16* Ah0 = (bf16*)(ws + OFF_AH0);
  bf16* Ah1 = Ar1;   // h1_in bf16 dead after D1
  bf16* Ah2 = Ar2;   // h2_in bf16 dead after D1
  // split-K partials in regions dead after D1 (A0/Wt0/W1r/W2r): 32 MB used,
  // ends at 33.6 MB < OFF_W01 (37.7 MB) -> W01/W12 untouched.
  float* P0 = (float*)(ws + 0);
  float* P1 = (float*)(ws + 16777216);

  float* o_h0  = out;
  float* o_h1  = out + (size_t)BB * NN;
  float* o_h2  = out + (size_t)2 * BB * NN;
  float* o_out = out + (size_t)3 * BB * NN;

  // --- fused prep (1 dispatch) ---
  PAll pa;
  int n8a = BB * ISZ / 8;
  int n8b = n8a + BB * NN / 8;
  int n8c = n8b + BB * NN / 8;
  int n8d = n8c + BB * NN / 8;
  pa.p[0] = {x,     A0,  ISZ, ISZ + NN, 0,   n8a};
  pa.p[1] = {h0_in, A0,  NN,  ISZ + NN, ISZ, n8b};
  pa.p[2] = {h1_in, Ar1, NN,  NN,       0,   n8c};
  pa.p[3] = {h2_in, Ar2, NN,  NN,       0,   n8d};
  pa.packBlocks = (n8d + 255) / 256;
  int s0 = 0;
  pa.d[0] = {i_to_h0,  nullptr, Wt0, NN,  ISZ + NN, 0,   0, ISZ / 32, s0}; s0 += (ISZ / 32) * (NN / 32);
  pa.d[1] = {h0_w,     nullptr, Wt0, NN,  ISZ + NN, ISZ, 1, NN / 32,  s0}; s0 += (NN / 32) * (NN / 32);
  pa.d[2] = {h1_w,     nullptr, W1r, NN,  NN,       0,   1, NN / 32,  s0}; s0 += (NN / 32) * (NN / 32);
  pa.d[3] = {h2_w,     nullptr, W2r, NN,  NN,       0,   1, NN / 32,  s0}; s0 += (NN / 32) * (NN / 32);
  pa.d[4] = {h0_to_h1, m01,     W01, NN,  NN,       0,   2, NN / 32,  s0}; s0 += (NN / 32) * (NN / 32);
  pa.d[5] = {h1_to_h2, m12,     W12, NN,  NN,       0,   2, NN / 32,  s0}; s0 += (NN / 32) * (NN / 32);
  pa.d[6] = {w_out,    nullptr, WtO, OSZ, NN,       0,   0, NN / 32,  s0}; s0 += (NN / 32) * (OSZ / 32);
  prep_all_k<<<pa.packBlocks + s0, 256, 0, stream>>>(pa);

  // --- D1: S0 (h0) + R1 + R2, 768 blocks of 8 waves, 128x128 ---
  GP pS0{A0,  Wt0, ISZ + NN, ISZ + NN, ISZ + NN, h0_in, h0_b, nullptr,
         o_h0, NN, Ah0, NN, 0};
  GP pR1{Ar1, W1r, NN, NN, NN, nullptr, nullptr, nullptr, o_h1, NN, nullptr, 0, 1};
  GP pR2{Ar2, W2r, NN, NN, NN, nullptr, nullptr, nullptr, o_h2, NN, nullptr, 0, 1};
  k_tri<<<dim3(NN / 128, BB / 128, 3), 512, 0, stream>>>(pS0, pR1, pR2);

  // --- D2: F1 = h0@W01 split-K=2 (512 blocks); combine with R1 -> h1 ---
  GP pG1a{Ah0,          W01,          NN / 2, NN, NN, nullptr, nullptr, nullptr, P0, NN, nullptr, 0, 1};
  GP pG1b{Ah0 + NN / 2, W01 + NN / 2, NN / 2, NN, NN, nullptr, nullptr, nullptr, P1, NN, nullptr, 0, 1};
  k_split<<<dim3(NN / 128, BB / 128, 2), 512, 0, stream>>>(pG1a, pG1b);
  k_epi<<<BB * NN / 2048, 256, 0, stream>>>(P0, P1, o_h1, h1_in, h1_b, o_h1, Ah1);

  // --- D3: F2 = h1@W12 split-K=2; combine with R2 -> h2 ---
  GP pG2a{Ah1,          W12,          NN / 2, NN, NN, nullptr, nullptr, nullptr, P0, NN, nullptr, 0, 1};
  GP pG2b{Ah1 + NN / 2, W12 + NN / 2, NN / 2, NN, NN, nullptr, nullptr, nullptr, P1, NN, nullptr, 0, 1};
  k_split<<<dim3(NN / 128, BB / 128, 2), 512, 0, stream>>>(pG2a, pG2b);
  k_epi<<<BB * NN / 2048, 256, 0, stream>>>(P0, P1, o_h2, h2_in, h2_b, o_h2, Ah2);

  // --- D4: out = h2 @ w_out ---
  GP pO{Ah2, WtO, NN, NN, NN, nullptr, nullptr, nullptr, o_out, OSZ, nullptr, 0, 1};
  k_out<<<dim3(OSZ / 64, BB / 32), 512, 0, stream>>>(pO);
}

// Round 10
// 233.576 us; speedup vs baseline: 1.3303x; 1.1030x over previous
//
#include <hip/hip_runtime.h>
#include <hip/hip_bf16.h>
#include <stdint.h>

typedef __bf16 bf16;
typedef __bf16 bf16x8 __attribute__((ext_vector_type(8)));
typedef float f32x4 __attribute__((ext_vector_type(4)));

#define BB   2048
#define ISZ  512
#define NN   2048
#define OSZ  128

// ---------------------------------------------------------------------------
// Fused prep: 4 pack regions (fp32 -> bf16, 8 elems/thread) + 7 transposes
// ---------------------------------------------------------------------------
struct PackD { const float* src; bf16* dst; int W, ld, off, n8; };
struct TD    { const float* src; const float* msk; bf16* dst;
               int Ncols, ld_dst, k_off, mode, ntx, start; };
struct PAll  { PackD p[4]; TD d[7]; int packBlocks; };

__global__ __launch_bounds__(256) void prep_all_k(PAll a) {
  if ((int)blockIdx.x < a.packBlocks) {
    int idx = blockIdx.x * 256 + threadIdx.x;
    PackD d = a.p[0]; int base = 0;
#pragma unroll
    for (int i = 1; i < 4; ++i) if (idx >= a.p[i - 1].n8) { d = a.p[i]; base = a.p[i - 1].n8; }
    if (idx >= d.n8) return;
    int e = (idx - base) * 8;
    int m = e / d.W;
    int c = e - m * d.W;
    const float4 v0 = *reinterpret_cast<const float4*>(d.src + e);
    const float4 v1 = *reinterpret_cast<const float4*>(d.src + e + 4);
    bf16x8 o;
    o[0] = (bf16)v0.x; o[1] = (bf16)v0.y; o[2] = (bf16)v0.z; o[3] = (bf16)v0.w;
    o[4] = (bf16)v1.x; o[5] = (bf16)v1.y; o[6] = (bf16)v1.z; o[7] = (bf16)v1.w;
    *reinterpret_cast<bf16x8*>(d.dst + (size_t)m * d.ld + d.off + c) = o;
    return;
  }
  int bid = blockIdx.x - a.packBlocks;
  TD d = a.d[0];
#pragma unroll
  for (int i = 1; i < 7; ++i) if (bid >= a.d[i].start) d = a.d[i];
  int local = bid - d.start;
  int k0 = (local % d.ntx) * 32;
  int n0 = (local / d.ntx) * 32;
  __shared__ float t[32][33];
  const int tx = threadIdx.x & 31, ty = threadIdx.x >> 5;
#pragma unroll
  for (int i = 0; i < 4; ++i) {
    int k = k0 + ty + i * 8;
    float v = d.src[(size_t)k * d.Ncols + n0 + tx];
    if (d.mode == 1 && k == (n0 + tx)) v = 0.f;
    if (d.mode == 2) v *= d.msk[(size_t)k * d.Ncols + n0 + tx];
    t[ty + i * 8][tx] = v;
  }
  __syncthreads();
#pragma unroll
  for (int i = 0; i < 4; ++i) {
    int n = n0 + ty + i * 8;
    d.dst[(size_t)n * d.ld_dst + d.k_off + k0 + tx] = (bf16)t[tx][ty + i * 8];
  }
}

// ---------------------------------------------------------------------------
// GEMM descriptor; epi 0: pre = acc + bias[col] (+ radd);
// h = hin*0.9 + relu(pre)*0.1 -> fp32 outf + bf16 nxt.   epi 1: fp32 acc.
// ---------------------------------------------------------------------------
struct GP {
  const bf16* A; const bf16* B;
  int K, lda, ldb;
  const float* hin; const float* bias; const float* radd;
  float* outf; int ld_out;
  bf16* nxt; int ld_nxt;
  int epi;
};

__device__ __forceinline__ void gload16(const bf16* g, bf16* l) {
  __builtin_amdgcn_global_load_lds(
      (const __attribute__((address_space(1))) void*)g,
      (__attribute__((address_space(3))) void*)l, 16, 0, 0);
}

__device__ __forceinline__ void epilogue_store(const GP& p, int row, int col, float v) {
  size_t oidx = (size_t)row * p.ld_out + col;
  if (p.epi == 0) {
    float pre = v + p.bias[col];
    if (p.radd) pre += p.radd[oidx];
    float h = p.hin[oidx] * 0.9f + fmaxf(pre, 0.f) * 0.1f;
    p.outf[oidx] = h;
    p.nxt[(size_t)row * p.ld_nxt + col] = (bf16)h;
  } else {
    p.outf[oidx] = v;
  }
}

// ---------------------------------------------------------------------------
// R10 body: 128x128 tile, 8 waves = 2x2 spatial (wave-tile 64x64) x 2 K-
// slices, BK=64, double-buffered 64 KB LDS, counted vmcnt, cross-slice LDS
// reduce.  Body verified correct in R5 (gemm_t8); transplanted into the
// proven 768/512-block launch geometry.  Swizzle (verified R5): stage lane
// l -> row l>>3, col slot (l&7)^(l>>3); read slot (4ks+(l>>4))^(frow&7)
// -> 2-way aliasing only (free), coalescing preserved (8 lanes = 128B row).
// ---------------------------------------------------------------------------
__device__ __forceinline__ void gemm_ks(const GP p) {
  __shared__ __align__(16) bf16 sm[2][2][128][64];    // [buf][A/B][row][col] = 64 KB
  const int lane = threadIdx.x & 63;
  const int wave = threadIdx.x >> 6;                  // 0..7
  const int ks = wave >> 2;                           // K-slice 0/1
  const int sp = wave & 3;                            // spatial 2x2
  const int gx = gridDim.x, nwg = gx * gridDim.y;     // 256 per z (%8==0)
  const int lid = blockIdx.x + gx * blockIdx.y;
  const int q = nwg >> 3;
  const int swz = (lid & 7) * q + (lid >> 3);
  const int m0 = (swz / gx) * 128, n0 = (swz % gx) * 128;
  const int wm0 = (sp >> 1) * 64, wn0 = (sp & 1) * 64;
  const int srow = lane >> 3;                         // 0..7 in 8-row chunk
  const int scol = ((lane & 7) ^ srow) * 8;           // swizzled source col
  const int frow = lane & 15;
  const int rcol = (((ks << 2) + (lane >> 4)) ^ (frow & 7)) * 8;

  f32x4 acc[4][4];
#pragma unroll
  for (int i = 0; i < 4; ++i)
#pragma unroll
    for (int j = 0; j < 4; ++j)
#pragma unroll
      for (int r = 0; r < 4; ++r) acc[i][j][r] = 0.f;

  auto stage = [&](int buf, int t) {
    const int k0 = t * 64;
#pragma unroll
    for (int h = 0; h < 2; ++h) {
      const int c = wave + h * 8;
      gload16(p.A + (size_t)(m0 + c * 8 + srow) * p.lda + k0 + scol,
              &sm[buf][0][0][0] + c * 512);
      gload16(p.B + (size_t)(n0 + c * 8 + srow) * p.ldb + k0 + scol,
              &sm[buf][1][0][0] + c * 512);
    }
  };

  const int nt = p.K / 64;
  stage(0, 0);
  int cur = 0;
  for (int t = 0; t < nt; ++t) {
    if (t + 1 < nt) {
      stage(cur ^ 1, t + 1);
      asm volatile("s_waitcnt vmcnt(4)" ::: "memory");   // my tile-t loads landed
    } else {
      asm volatile("s_waitcnt vmcnt(0)" ::: "memory");
    }
    __builtin_amdgcn_s_barrier();

    bf16x8 af[4], bf_[4];
#pragma unroll
    for (int i = 0; i < 4; ++i)
      af[i] = *reinterpret_cast<const bf16x8*>(&sm[cur][0][wm0 + i * 16 + frow][rcol]);
#pragma unroll
    for (int j = 0; j < 4; ++j)
      bf_[j] = *reinterpret_cast<const bf16x8*>(&sm[cur][1][wn0 + j * 16 + frow][rcol]);
#pragma unroll
    for (int i = 0; i < 4; ++i)
#pragma unroll
      for (int j = 0; j < 4; ++j)
        acc[i][j] = __builtin_amdgcn_mfma_f32_16x16x32_bf16(af[i], bf_[j], acc[i][j], 0, 0, 0);

    if (t + 1 < nt) {
      asm volatile("s_waitcnt lgkmcnt(0)" ::: "memory");
      __builtin_amdgcn_s_barrier();
    }
    cur ^= 1;
  }

  // cross-K-slice reduce via LDS (staging buffers dead now)
  asm volatile("s_waitcnt lgkmcnt(0)" ::: "memory");
  __builtin_amdgcn_s_barrier();
  float* red = (float*)&sm[0][0][0][0];               // 64 KB scratch
  if (ks == 1) {
#pragma unroll
    for (int i = 0; i < 4; ++i)
#pragma unroll
      for (int j = 0; j < 4; ++j)
        *reinterpret_cast<f32x4*>(&red[sp * 4096 + (i * 4 + j) * 256 + lane * 4]) = acc[i][j];
    asm volatile("s_waitcnt lgkmcnt(0)" ::: "memory");
  }
  __builtin_amdgcn_s_barrier();
  if (ks == 0) {
#pragma unroll
    for (int i = 0; i < 4; ++i)
#pragma unroll
      for (int j = 0; j < 4; ++j) {
        f32x4 o = *reinterpret_cast<const f32x4*>(&red[sp * 4096 + (i * 4 + j) * 256 + lane * 4]);
#pragma unroll
        for (int r = 0; r < 4; ++r) acc[i][j][r] += o[r];
#pragma unroll
        for (int r = 0; r < 4; ++r)
          epilogue_store(p, m0 + wm0 + i * 16 + (lane >> 4) * 4 + r,
                         n0 + wn0 + j * 16 + (lane & 15), acc[i][j][r]);
      }
  }
}

// small output GEMM — proven R9 body (k-slot swizzled, conflict-free)
template<int BM, int BN>
__device__ __forceinline__ void gemm_body8(const GP p) {
  constexpr int BK = 32;
  constexpr int WM = BM / 2, WN = BN / 4;
  constexpr int FM = WM / 16, FN = WN / 16;
  __shared__ bf16 As[2][BM][BK];
  __shared__ bf16 Bs[2][BN][BK];
  const int lane = threadIdx.x & 63;
  const int wave = threadIdx.x >> 6;
  const int m0 = blockIdx.y * BM, n0 = blockIdx.x * BN;
  const int wm0 = (wave >> 2) * WM, wn0 = (wave & 3) * WN;
  const int srow = lane >> 2;
  const int scolE = (((lane & 3) ^ ((lane >> 3) & 3)) * 8);
  const int frow = lane & 15;
  const int rcolE = (((lane >> 4) ^ ((frow >> 1) & 3)) * 8);

  f32x4 acc[FM][FN];
#pragma unroll
  for (int i = 0; i < FM; ++i)
#pragma unroll
    for (int j = 0; j < FN; ++j)
#pragma unroll
      for (int r = 0; r < 4; ++r) acc[i][j][r] = 0.f;

  auto stage = [&](int buf, int t) {
    const int k0 = t * BK;
#pragma unroll
    for (int c = wave; c < BM / 16; c += 8) {
      const bf16* g = p.A + (size_t)(m0 + c * 16 + srow) * p.lda + k0 + scolE;
      gload16(g, &As[buf][0][0] + c * 512);
    }
#pragma unroll
    for (int c = wave; c < BN / 16; c += 8) {
      const bf16* g = p.B + (size_t)(n0 + c * 16 + srow) * p.ldb + k0 + scolE;
      gload16(g, &Bs[buf][0][0] + c * 512);
    }
  };

  const int nt = p.K / BK;
  stage(0, 0);
  __syncthreads();
  int cur = 0;
  for (int t = 0; t < nt; ++t) {
    if (t + 1 < nt) stage(cur ^ 1, t + 1);
    bf16x8 af[FM], bfrag[FN];
#pragma unroll
    for (int i = 0; i < FM; ++i)
      af[i] = *reinterpret_cast<const bf16x8*>(&As[cur][wm0 + i * 16 + frow][rcolE]);
#pragma unroll
    for (int j = 0; j < FN; ++j)
      bfrag[j] = *reinterpret_cast<const bf16x8*>(&Bs[cur][wn0 + j * 16 + frow][rcolE]);
#pragma unroll
    for (int i = 0; i < FM; ++i)
#pragma unroll
      for (int j = 0; j < FN; ++j)
        acc[i][j] = __builtin_amdgcn_mfma_f32_16x16x32_bf16(af[i], bfrag[j], acc[i][j], 0, 0, 0);
    __syncthreads();
    cur ^= 1;
  }

#pragma unroll
  for (int i = 0; i < FM; ++i)
#pragma unroll
    for (int j = 0; j < FN; ++j)
#pragma unroll
      for (int r = 0; r < 4; ++r)
        epilogue_store(p, m0 + wm0 + i * 16 + (lane >> 4) * 4 + r,
                       n0 + wn0 + j * 16 + (lane & 15), acc[i][j][r]);
}

__global__ __launch_bounds__(512) void k_tri(GP p0, GP p1, GP p2) {
  GP p;
  if (blockIdx.z == 0) p = p0;
  else if (blockIdx.z == 1) p = p1;
  else p = p2;
  gemm_ks(p);
}

__global__ __launch_bounds__(512) void k_split(GP p0, GP p1) {
  gemm_ks(blockIdx.z == 0 ? p0 : p1);
}

__global__ __launch_bounds__(512) void k_out(GP p) { gemm_body8<32, 64>(p); }

// elementwise: h = hin*0.9 + relu(P0+P1+radd+bias)*0.1 -> fp32 out + bf16 nxt
__global__ __launch_bounds__(256) void k_epi(const float* __restrict__ P0,
                                             const float* __restrict__ P1,
                                             const float* __restrict__ radd,
                                             const float* __restrict__ hin,
                                             const float* __restrict__ bias,
                                             float* __restrict__ outf,
                                             bf16* __restrict__ nxt) {
  int e = (blockIdx.x * 256 + threadIdx.x) * 8;
  int colb = e & (NN - 1);
  const float4 a0 = *reinterpret_cast<const float4*>(P0 + e);
  const float4 a1 = *reinterpret_cast<const float4*>(P0 + e + 4);
  const float4 b0 = *reinterpret_cast<const float4*>(P1 + e);
  const float4 b1 = *reinterpret_cast<const float4*>(P1 + e + 4);
  const float4 r0 = *reinterpret_cast<const float4*>(radd + e);
  const float4 r1 = *reinterpret_cast<const float4*>(radd + e + 4);
  const float4 h0 = *reinterpret_cast<const float4*>(hin + e);
  const float4 h1 = *reinterpret_cast<const float4*>(hin + e + 4);
  const float4 c0 = *reinterpret_cast<const float4*>(bias + colb);
  const float4 c1 = *reinterpret_cast<const float4*>(bias + colb + 4);
  float pa[8] = {a0.x, a0.y, a0.z, a0.w, a1.x, a1.y, a1.z, a1.w};
  float pb[8] = {b0.x, b0.y, b0.z, b0.w, b1.x, b1.y, b1.z, b1.w};
  float pr[8] = {r0.x, r0.y, r0.z, r0.w, r1.x, r1.y, r1.z, r1.w};
  float ph[8] = {h0.x, h0.y, h0.z, h0.w, h1.x, h1.y, h1.z, h1.w};
  float pc[8] = {c0.x, c0.y, c0.z, c0.w, c1.x, c1.y, c1.z, c1.w};
  float4 o0, o1;
  bf16x8 nb;
#pragma unroll
  for (int j = 0; j < 8; ++j) {
    float pre = pa[j] + pb[j] + pr[j] + pc[j];
    float h = ph[j] * 0.9f + fmaxf(pre, 0.f) * 0.1f;
    (j < 4 ? (&o0.x)[j] : (&o1.x)[j - 4]) = h;
    nb[j] = (bf16)h;
  }
  *reinterpret_cast<float4*>(outf + e) = o0;
  *reinterpret_cast<float4*>(outf + e + 4) = o1;
  *reinterpret_cast<bf16x8*>(nxt + e) = nb;
}

// ---------------------------------------------------------------------------
extern "C" void kernel_launch(void* const* d_in, const int* in_sizes, int n_in,
                              void* d_out, int out_size, void* d_ws, size_t ws_size,
                              hipStream_t stream) {
  const float* x        = (const float*)d_in[0];
  const float* h0_in    = (const float*)d_in[1];
  const float* h1_in    = (const float*)d_in[2];
  const float* h2_in    = (const float*)d_in[3];
  const float* i_to_h0  = (const float*)d_in[4];
  const float* h0_w     = (const float*)d_in[5];
  const float* h0_b     = (const float*)d_in[6];
  const float* h0_to_h1 = (const float*)d_in[7];
  const float* h1_w     = (const float*)d_in[8];
  const float* h1_b     = (const float*)d_in[9];
  const float* h1_to_h2 = (const float*)d_in[10];
  const float* h2_w     = (const float*)d_in[11];
  const float* h2_b     = (const float*)d_in[12];
  const float* w_out    = (const float*)d_in[13];
  const float* m01      = (const float*)d_in[14];
  const float* m12      = (const float*)d_in[15];
  float* out = (float*)d_out;

  uint8_t* ws = (uint8_t*)d_ws;
  constexpr size_t OFF_A0  = 0;                    // [2048][2560] A of S0
  constexpr size_t OFF_W0  = OFF_A0 + 10485760;    // [2048][2560] B^T of S0
  constexpr size_t OFF_W1R = OFF_W0 + 10485760;    // [2048][2048] h1_w'^T
  constexpr size_t OFF_W2R = OFF_W1R + 8388608;    // [2048][2048] h2_w'^T
  constexpr size_t OFF_W01 = OFF_W2R + 8388608;    // [2048][2048] h01m^T
  constexpr size_t OFF_W12 = OFF_W01 + 8388608;    // [2048][2048] h12m^T
  constexpr size_t OFF_WO  = OFF_W12 + 8388608;    // [128][2048]  w_out^T
  constexpr size_t OFF_AR1 = OFF_WO + 524288;      // h1_in bf16 -> later h1 bf16
  constexpr size_t OFF_AR2 = OFF_AR1 + 8388608;    // h2_in bf16 -> later h2 bf16
  constexpr size_t OFF_AH0 = OFF_AR2 + 8388608;    // h0 bf16
  constexpr size_t WS_NEED = OFF_AH0 + 8388608;    // ~80.2 MB
  if (ws_size < WS_NEED) return;

  bf16* A0  = (bf16*)(ws + OFF_A0);
  bf16* Wt0 = (bf16*)(ws + OFF_W0);
  bf16* W1r = (bf16*)(ws + OFF_W1R);
  bf16* W2r = (bf16*)(ws + OFF_W2R);
  bf16* W01 = (bf16*)(ws + OFF_W01);
  bf16* W12 = (bf16*)(ws + OFF_W12);
  bf16* WtO = (bf16*)(ws + OFF_WO);
  bf16* Ar1 = (bf16*)(ws + OFF_AR1);
  bf16* Ar2 = (bf16*)(ws + OFF_AR2);
  bf16* Ah0 = (bf16*)(ws + OFF_AH0);
  bf16* Ah1 = Ar1;   // h1_in bf16 dead after D1
  bf16* Ah2 = Ar2;   // h2_in bf16 dead after D1
  // split-K partials in regions dead after D1 (A0/Wt0/W1r/W2r): 32 MB used,
  // ends at 33.6 MB < OFF_W01 (37.7 MB) -> W01/W12 untouched.
  float* P0 = (float*)(ws + 0);
  float* P1 = (float*)(ws + 16777216);

  float* o_h0  = out;
  float* o_h1  = out + (size_t)BB * NN;
  float* o_h2  = out + (size_t)2 * BB * NN;
  float* o_out = out + (size_t)3 * BB * NN;

  // --- fused prep (1 dispatch) ---
  PAll pa;
  int n8a = BB * ISZ / 8;
  int n8b = n8a + BB * NN / 8;
  int n8c = n8b + BB * NN / 8;
  int n8d = n8c + BB * NN / 8;
  pa.p[0] = {x,     A0,  ISZ, ISZ + NN, 0,   n8a};
  pa.p[1] = {h0_in, A0,  NN,  ISZ + NN, ISZ, n8b};
  pa.p[2] = {h1_in, Ar1, NN,  NN,       0,   n8c};
  pa.p[3] = {h2_in, Ar2, NN,  NN,       0,   n8d};
  pa.packBlocks = (n8d + 255) / 256;
  int s0 = 0;
  pa.d[0] = {i_to_h0,  nullptr, Wt0, NN,  ISZ + NN, 0,   0, ISZ / 32, s0}; s0 += (ISZ / 32) * (NN / 32);
  pa.d[1] = {h0_w,     nullptr, Wt0, NN,  ISZ + NN, ISZ, 1, NN / 32,  s0}; s0 += (NN / 32) * (NN / 32);
  pa.d[2] = {h1_w,     nullptr, W1r, NN,  NN,       0,   1, NN / 32,  s0}; s0 += (NN / 32) * (NN / 32);
  pa.d[3] = {h2_w,     nullptr, W2r, NN,  NN,       0,   1, NN / 32,  s0}; s0 += (NN / 32) * (NN / 32);
  pa.d[4] = {h0_to_h1, m01,     W01, NN,  NN,       0,   2, NN / 32,  s0}; s0 += (NN / 32) * (NN / 32);
  pa.d[5] = {h1_to_h2, m12,     W12, NN,  NN,       0,   2, NN / 32,  s0}; s0 += (NN / 32) * (NN / 32);
  pa.d[6] = {w_out,    nullptr, WtO, OSZ, NN,       0,   0, NN / 32,  s0}; s0 += (NN / 32) * (OSZ / 32);
  prep_all_k<<<pa.packBlocks + s0, 256, 0, stream>>>(pa);

  // --- D1: S0 (h0) + R1 + R2, 768 blocks of 8 waves, 128x128 K-split body ---
  GP pS0{A0,  Wt0, ISZ + NN, ISZ + NN, ISZ + NN, h0_in, h0_b, nullptr,
         o_h0, NN, Ah0, NN, 0};
  GP pR1{Ar1, W1r, NN, NN, NN, nullptr, nullptr, nullptr, o_h1, NN, nullptr, 0, 1};
  GP pR2{Ar2, W2r, NN, NN, NN, nullptr, nullptr, nullptr, o_h2, NN, nullptr, 0, 1};
  k_tri<<<dim3(NN / 128, BB / 128, 3), 512, 0, stream>>>(pS0, pR1, pR2);

  // --- D2: F1 = h0@W01 split-K=2 (512 blocks); combine with R1 -> h1 ---
  GP pG1a{Ah0,          W01,          NN / 2, NN, NN, nullptr, nullptr, nullptr, P0, NN, nullptr, 0, 1};
  GP pG1b{Ah0 + NN / 2, W01 + NN / 2, NN / 2, NN, NN, nullptr, nullptr, nullptr, P1, NN, nullptr, 0, 1};
  k_split<<<dim3(NN / 128, BB / 128, 2), 512, 0, stream>>>(pG1a, pG1b);
  k_epi<<<BB * NN / 2048, 256, 0, stream>>>(P0, P1, o_h1, h1_in, h1_b, o_h1, Ah1);

  // --- D3: F2 = h1@W12 split-K=2; combine with R2 -> h2 ---
  GP pG2a{Ah1,          W12,          NN / 2, NN, NN, nullptr, nullptr, nullptr, P0, NN, nullptr, 0, 1};
  GP pG2b{Ah1 + NN / 2, W12 + NN / 2, NN / 2, NN, NN, nullptr, nullptr, nullptr, P1, NN, nullptr, 0, 1};
  k_split<<<dim3(NN / 128, BB / 128, 2), 512, 0, stream>>>(pG2a, pG2b);
  k_epi<<<BB * NN / 2048, 256, 0, stream>>>(P0, P1, o_h2, h2_in, h2_b, o_h2, Ah2);

  // --- D4: out = h2 @ w_out ---
  GP pO{Ah2, WtO, NN, NN, NN, nullptr, nullptr, nullptr, o_out, OSZ, nullptr, 0, 1};
  k_out<<<dim3(OSZ / 64, BB / 32), 512, 0, stream>>>(pO);
}

// Round 11
// 215.483 us; speedup vs baseline: 1.4420x; 1.0840x over previous
//
#include <hip/hip_runtime.h>
#include <hip/hip_bf16.h>
#include <stdint.h>

typedef __bf16 bf16;
typedef __bf16 bf16x8 __attribute__((ext_vector_type(8)));
typedef float f32x4 __attribute__((ext_vector_type(4)));

#define BB   2048
#define ISZ  512
#define NN   2048
#define OSZ  128

// ---------------------------------------------------------------------------
// Fused prep: 4 pack regions (fp32 -> bf16, 8 elems/thread) + 7 transposes.
// R11: transpose tile = 128(k) x 32(n), wide I/O:
//   read  : float4 per lane, 128B/8-lane segments (unchanged coalescing)
//   write : 2x bf16x8 per lane (32B contiguous), 8 lanes = 256B row chunk
//   (was: 2B scalar stores, 64B per row chunk -> transaction-bound)
// ---------------------------------------------------------------------------
struct PackD { const float* src; bf16* dst; int W, ld, off, n8; };
struct TD    { const float* src; const float* msk; bf16* dst;
               int Ncols, ld_dst, k_off, mode, ntk, start; };  // ntk = K/128
struct PAll  { PackD p[4]; TD d[7]; int packBlocks; };

__global__ __launch_bounds__(256) void prep_all_k(PAll a) {
  if ((int)blockIdx.x < a.packBlocks) {
    int idx = blockIdx.x * 256 + threadIdx.x;
    PackD d = a.p[0]; int base = 0;
#pragma unroll
    for (int i = 1; i < 4; ++i) if (idx >= a.p[i - 1].n8) { d = a.p[i]; base = a.p[i - 1].n8; }
    if (idx >= d.n8) return;
    int e = (idx - base) * 8;
    int m = e / d.W;
    int c = e - m * d.W;
    const float4 v0 = *reinterpret_cast<const float4*>(d.src + e);
    const float4 v1 = *reinterpret_cast<const float4*>(d.src + e + 4);
    bf16x8 o;
    o[0] = (bf16)v0.x; o[1] = (bf16)v0.y; o[2] = (bf16)v0.z; o[3] = (bf16)v0.w;
    o[4] = (bf16)v1.x; o[5] = (bf16)v1.y; o[6] = (bf16)v1.z; o[7] = (bf16)v1.w;
    *reinterpret_cast<bf16x8*>(d.dst + (size_t)m * d.ld + d.off + c) = o;
    return;
  }
  // ---- transpose path: tile 128(k) x 32(n) ----
  int bid = blockIdx.x - a.packBlocks;
  TD d = a.d[0];
#pragma unroll
  for (int i = 1; i < 7; ++i) if (bid >= a.d[i].start) d = a.d[i];
  int local = bid - d.start;
  int k0 = (local % d.ntk) * 128;
  int n0 = (local / d.ntk) * 32;
  __shared__ float t[128][33];
  const int tx8 = threadIdx.x & 7;       // 0..7
  const int kr  = threadIdx.x >> 3;      // 0..31
  const int nc  = n0 + tx8 * 4;
#pragma unroll
  for (int i = 0; i < 4; ++i) {
    int k = k0 + kr + 32 * i;
    float4 v = *reinterpret_cast<const float4*>(d.src + (size_t)k * d.Ncols + nc);
    if (d.mode == 2) {
      float4 m = *reinterpret_cast<const float4*>(d.msk + (size_t)k * d.Ncols + nc);
      v.x *= m.x; v.y *= m.y; v.z *= m.z; v.w *= m.w;
    } else if (d.mode == 1) {
      if (k == nc)     v.x = 0.f;
      if (k == nc + 1) v.y = 0.f;
      if (k == nc + 2) v.z = 0.f;
      if (k == nc + 3) v.w = 0.f;
    }
    float* r = &t[kr + 32 * i][tx8 * 4];
    r[0] = v.x; r[1] = v.y; r[2] = v.z; r[3] = v.w;
  }
  __syncthreads();
  const int n  = threadIdx.x >> 3;       // 0..31 dst row within tile
  const int kc = (threadIdx.x & 7) * 16; // k chunk
  bf16x8 o0, o1;
#pragma unroll
  for (int j = 0; j < 8; ++j) {
    o0[j] = (bf16)t[kc + j][n];
    o1[j] = (bf16)t[kc + 8 + j][n];
  }
  bf16* dp = d.dst + (size_t)(n0 + n) * d.ld_dst + d.k_off + k0 + kc;
  *reinterpret_cast<bf16x8*>(dp) = o0;
  *reinterpret_cast<bf16x8*>(dp + 8) = o1;
}

// ---------------------------------------------------------------------------
// GEMM descriptor; epi 0: pre = acc + bias[col] (+ radd);
// h = hin*0.9 + relu(pre)*0.1 -> fp32 outf + bf16 nxt.   epi 1: fp32 acc.
// ---------------------------------------------------------------------------
struct GP {
  const bf16* A; const bf16* B;
  int K, lda, ldb;
  const float* hin; const float* bias; const float* radd;
  float* outf; int ld_out;
  bf16* nxt; int ld_nxt;
  int epi;
};

__device__ __forceinline__ void gload16(const bf16* g, bf16* l) {
  __builtin_amdgcn_global_load_lds(
      (const __attribute__((address_space(1))) void*)g,
      (__attribute__((address_space(3))) void*)l, 16, 0, 0);
}

__device__ __forceinline__ void epilogue_store(const GP& p, int row, int col, float v) {
  size_t oidx = (size_t)row * p.ld_out + col;
  if (p.epi == 0) {
    float pre = v + p.bias[col];
    if (p.radd) pre += p.radd[oidx];
    float h = p.hin[oidx] * 0.9f + fmaxf(pre, 0.f) * 0.1f;
    p.outf[oidx] = h;
    p.nxt[(size_t)row * p.ld_nxt + col] = (bf16)h;
  } else {
    p.outf[oidx] = v;
  }
}

// ---------------------------------------------------------------------------
// R10 winner body: 128x128 tile, 8 waves = 2x2 spatial (wave-tile 64x64) x 2
// K-slices, BK=64, dbuf 64 KB LDS, counted vmcnt, cross-slice LDS reduce.
// Swizzle: stage lane l -> row l>>3, col slot (l&7)^(l>>3); read slot
// (4ks+(l>>4))^(frow&7) -> conflict-free, coalescing preserved.
// Measured R10: D1 89 us, MfmaUtil 26%, SQ_LDS_BANK_CONFLICT 0.
// ---------------------------------------------------------------------------
__device__ __forceinline__ void gemm_ks(const GP p) {
  __shared__ __align__(16) bf16 sm[2][2][128][64];    // [buf][A/B][row][col] = 64 KB
  const int lane = threadIdx.x & 63;
  const int wave = threadIdx.x >> 6;                  // 0..7
  const int ks = wave >> 2;                           // K-slice 0/1
  const int sp = wave & 3;                            // spatial 2x2
  const int gx = gridDim.x, nwg = gx * gridDim.y;     // 256 per z (%8==0)
  const int lid = blockIdx.x + gx * blockIdx.y;
  const int q = nwg >> 3;
  const int swz = (lid & 7) * q + (lid >> 3);
  const int m0 = (swz / gx) * 128, n0 = (swz % gx) * 128;
  const int wm0 = (sp >> 1) * 64, wn0 = (sp & 1) * 64;
  const int srow = lane >> 3;                         // 0..7 in 8-row chunk
  const int scol = ((lane & 7) ^ srow) * 8;           // swizzled source col
  const int frow = lane & 15;
  const int rcol = (((ks << 2) + (lane >> 4)) ^ (frow & 7)) * 8;

  f32x4 acc[4][4];
#pragma unroll
  for (int i = 0; i < 4; ++i)
#pragma unroll
    for (int j = 0; j < 4; ++j)
#pragma unroll
      for (int r = 0; r < 4; ++r) acc[i][j][r] = 0.f;

  auto stage = [&](int buf, int t) {
    const int k0 = t * 64;
#pragma unroll
    for (int h = 0; h < 2; ++h) {
      const int c = wave + h * 8;
      gload16(p.A + (size_t)(m0 + c * 8 + srow) * p.lda + k0 + scol,
              &sm[buf][0][0][0] + c * 512);
      gload16(p.B + (size_t)(n0 + c * 8 + srow) * p.ldb + k0 + scol,
              &sm[buf][1][0][0] + c * 512);
    }
  };

  const int nt = p.K / 64;
  stage(0, 0);
  int cur = 0;
  for (int t = 0; t < nt; ++t) {
    if (t + 1 < nt) {
      stage(cur ^ 1, t + 1);
      asm volatile("s_waitcnt vmcnt(4)" ::: "memory");   // my tile-t loads landed
    } else {
      asm volatile("s_waitcnt vmcnt(0)" ::: "memory");
    }
    __builtin_amdgcn_s_barrier();

    bf16x8 af[4], bf_[4];
#pragma unroll
    for (int i = 0; i < 4; ++i)
      af[i] = *reinterpret_cast<const bf16x8*>(&sm[cur][0][wm0 + i * 16 + frow][rcol]);
#pragma unroll
    for (int j = 0; j < 4; ++j)
      bf_[j] = *reinterpret_cast<const bf16x8*>(&sm[cur][1][wn0 + j * 16 + frow][rcol]);
#pragma unroll
    for (int i = 0; i < 4; ++i)
#pragma unroll
      for (int j = 0; j < 4; ++j)
        acc[i][j] = __builtin_amdgcn_mfma_f32_16x16x32_bf16(af[i], bf_[j], acc[i][j], 0, 0, 0);

    if (t + 1 < nt) {
      asm volatile("s_waitcnt lgkmcnt(0)" ::: "memory");
      __builtin_amdgcn_s_barrier();
    }
    cur ^= 1;
  }

  // cross-K-slice reduce via LDS (staging buffers dead now)
  asm volatile("s_waitcnt lgkmcnt(0)" ::: "memory");
  __builtin_amdgcn_s_barrier();
  float* red = (float*)&sm[0][0][0][0];               // 64 KB scratch
  if (ks == 1) {
#pragma unroll
    for (int i = 0; i < 4; ++i)
#pragma unroll
      for (int j = 0; j < 4; ++j)
        *reinterpret_cast<f32x4*>(&red[sp * 4096 + (i * 4 + j) * 256 + lane * 4]) = acc[i][j];
    asm volatile("s_waitcnt lgkmcnt(0)" ::: "memory");
  }
  __builtin_amdgcn_s_barrier();
  if (ks == 0) {
#pragma unroll
    for (int i = 0; i < 4; ++i)
#pragma unroll
      for (int j = 0; j < 4; ++j) {
        f32x4 o = *reinterpret_cast<const f32x4*>(&red[sp * 4096 + (i * 4 + j) * 256 + lane * 4]);
#pragma unroll
        for (int r = 0; r < 4; ++r) acc[i][j][r] += o[r];
#pragma unroll
        for (int r = 0; r < 4; ++r)
          epilogue_store(p, m0 + wm0 + i * 16 + (lane >> 4) * 4 + r,
                         n0 + wn0 + j * 16 + (lane & 15), acc[i][j][r]);
      }
  }
}

// small output GEMM — proven R9 body (k-slot swizzled, conflict-free)
template<int BM, int BN>
__device__ __forceinline__ void gemm_body8(const GP p) {
  constexpr int BK = 32;
  constexpr int WM = BM / 2, WN = BN / 4;
  constexpr int FM = WM / 16, FN = WN / 16;
  __shared__ bf16 As[2][BM][BK];
  __shared__ bf16 Bs[2][BN][BK];
  const int lane = threadIdx.x & 63;
  const int wave = threadIdx.x >> 6;
  const int m0 = blockIdx.y * BM, n0 = blockIdx.x * BN;
  const int wm0 = (wave >> 2) * WM, wn0 = (wave & 3) * WN;
  const int srow = lane >> 2;
  const int scolE = (((lane & 3) ^ ((lane >> 3) & 3)) * 8);
  const int frow = lane & 15;
  const int rcolE = (((lane >> 4) ^ ((frow >> 1) & 3)) * 8);

  f32x4 acc[FM][FN];
#pragma unroll
  for (int i = 0; i < FM; ++i)
#pragma unroll
    for (int j = 0; j < FN; ++j)
#pragma unroll
      for (int r = 0; r < 4; ++r) acc[i][j][r] = 0.f;

  auto stage = [&](int buf, int t) {
    const int k0 = t * BK;
#pragma unroll
    for (int c = wave; c < BM / 16; c += 8) {
      const bf16* g = p.A + (size_t)(m0 + c * 16 + srow) * p.lda + k0 + scolE;
      gload16(g, &As[buf][0][0] + c * 512);
    }
#pragma unroll
    for (int c = wave; c < BN / 16; c += 8) {
      const bf16* g = p.B + (size_t)(n0 + c * 16 + srow) * p.ldb + k0 + scolE;
      gload16(g, &Bs[buf][0][0] + c * 512);
    }
  };

  const int nt = p.K / BK;
  stage(0, 0);
  __syncthreads();
  int cur = 0;
  for (int t = 0; t < nt; ++t) {
    if (t + 1 < nt) stage(cur ^ 1, t + 1);
    bf16x8 af[FM], bfrag[FN];
#pragma unroll
    for (int i = 0; i < FM; ++i)
      af[i] = *reinterpret_cast<const bf16x8*>(&As[cur][wm0 + i * 16 + frow][rcolE]);
#pragma unroll
    for (int j = 0; j < FN; ++j)
      bfrag[j] = *reinterpret_cast<const bf16x8*>(&Bs[cur][wn0 + j * 16 + frow][rcolE]);
#pragma unroll
    for (int i = 0; i < FM; ++i)
#pragma unroll
      for (int j = 0; j < FN; ++j)
        acc[i][j] = __builtin_amdgcn_mfma_f32_16x16x32_bf16(af[i], bfrag[j], acc[i][j], 0, 0, 0);
    __syncthreads();
    cur ^= 1;
  }

#pragma unroll
  for (int i = 0; i < FM; ++i)
#pragma unroll
    for (int j = 0; j < FN; ++j)
#pragma unroll
      for (int r = 0; r < 4; ++r)
        epilogue_store(p, m0 + wm0 + i * 16 + (lane >> 4) * 4 + r,
                       n0 + wn0 + j * 16 + (lane & 15), acc[i][j][r]);
}

__global__ __launch_bounds__(512) void k_tri(GP p0, GP p1, GP p2) {
  GP p;
  if (blockIdx.z == 0) p = p0;
  else if (blockIdx.z == 1) p = p1;
  else p = p2;
  gemm_ks(p);
}

__global__ __launch_bounds__(512) void k_split(GP p0, GP p1) {
  gemm_ks(blockIdx.z == 0 ? p0 : p1);
}

__global__ __launch_bounds__(512) void k_out(GP p) { gemm_body8<32, 64>(p); }

// elementwise: h = hin*0.9 + relu(P0+P1+radd+bias)*0.1 -> fp32 out + bf16 nxt
__global__ __launch_bounds__(256) void k_epi(const float* __restrict__ P0,
                                             const float* __restrict__ P1,
                                             const float* __restrict__ radd,
                                             const float* __restrict__ hin,
                                             const float* __restrict__ bias,
                                             float* __restrict__ outf,
                                             bf16* __restrict__ nxt) {
  int e = (blockIdx.x * 256 + threadIdx.x) * 8;
  int colb = e & (NN - 1);
  const float4 a0 = *reinterpret_cast<const float4*>(P0 + e);
  const float4 a1 = *reinterpret_cast<const float4*>(P0 + e + 4);
  const float4 b0 = *reinterpret_cast<const float4*>(P1 + e);
  const float4 b1 = *reinterpret_cast<const float4*>(P1 + e + 4);
  const float4 r0 = *reinterpret_cast<const float4*>(radd + e);
  const float4 r1 = *reinterpret_cast<const float4*>(radd + e + 4);
  const float4 h0 = *reinterpret_cast<const float4*>(hin + e);
  const float4 h1 = *reinterpret_cast<const float4*>(hin + e + 4);
  const float4 c0 = *reinterpret_cast<const float4*>(bias + colb);
  const float4 c1 = *reinterpret_cast<const float4*>(bias + colb + 4);
  float pa[8] = {a0.x, a0.y, a0.z, a0.w, a1.x, a1.y, a1.z, a1.w};
  float pb[8] = {b0.x, b0.y, b0.z, b0.w, b1.x, b1.y, b1.z, b1.w};
  float pr[8] = {r0.x, r0.y, r0.z, r0.w, r1.x, r1.y, r1.z, r1.w};
  float ph[8] = {h0.x, h0.y, h0.z, h0.w, h1.x, h1.y, h1.z, h1.w};
  float pc[8] = {c0.x, c0.y, c0.z, c0.w, c1.x, c1.y, c1.z, c1.w};
  float4 o0, o1;
  bf16x8 nb;
#pragma unroll
  for (int j = 0; j < 8; ++j) {
    float pre = pa[j] + pb[j] + pr[j] + pc[j];
    float h = ph[j] * 0.9f + fmaxf(pre, 0.f) * 0.1f;
    (j < 4 ? (&o0.x)[j] : (&o1.x)[j - 4]) = h;
    nb[j] = (bf16)h;
  }
  *reinterpret_cast<float4*>(outf + e) = o0;
  *reinterpret_cast<float4*>(outf + e + 4) = o1;
  *reinterpret_cast<bf16x8*>(nxt + e) = nb;
}

// ---------------------------------------------------------------------------
extern "C" void kernel_launch(void* const* d_in, const int* in_sizes, int n_in,
                              void* d_out, int out_size, void* d_ws, size_t ws_size,
                              hipStream_t stream) {
  const float* x        = (const float*)d_in[0];
  const float* h0_in    = (const float*)d_in[1];
  const float* h1_in    = (const float*)d_in[2];
  const float* h2_in    = (const float*)d_in[3];
  const float* i_to_h0  = (const float*)d_in[4];
  const float* h0_w     = (const float*)d_in[5];
  const float* h0_b     = (const float*)d_in[6];
  const float* h0_to_h1 = (const float*)d_in[7];
  const float* h1_w     = (const float*)d_in[8];
  const float* h1_b     = (const float*)d_in[9];
  const float* h1_to_h2 = (const float*)d_in[10];
  const float* h2_w     = (const float*)d_in[11];
  const float* h2_b     = (const float*)d_in[12];
  const float* w_out    = (const float*)d_in[13];
  const float* m01      = (const float*)d_in[14];
  const float* m12      = (const float*)d_in[15];
  float* out = (float*)d_out;

  uint8_t* ws = (uint8_t*)d_ws;
  constexpr size_t OFF_A0  = 0;                    // [2048][2560] A of S0
  constexpr size_t OFF_W0  = OFF_A0 + 10485760;    // [2048][2560] B^T of S0
  constexpr size_t OFF_W1R = OFF_W0 + 10485760;    // [2048][2048] h1_w'^T
  constexpr size_t OFF_W2R = OFF_W1R + 8388608;    // [2048][2048] h2_w'^T
  constexpr size_t OFF_W01 = OFF_W2R + 8388608;    // [2048][2048] h01m^T
  constexpr size_t OFF_W12 = OFF_W01 + 8388608;    // [2048][2048] h12m^T
  constexpr size_t OFF_WO  = OFF_W12 + 8388608;    // [128][2048]  w_out^T
  constexpr size_t OFF_AR1 = OFF_WO + 524288;      // h1_in bf16 -> later h1 bf16
  constexpr size_t OFF_AR2 = OFF_AR1 + 8388608;    // h2_in bf16 -> later h2 bf16
  constexpr size_t OFF_AH0 = OFF_AR2 + 8388608;    // h0 bf16
  constexpr size_t WS_NEED = OFF_AH0 + 8388608;    // ~80.2 MB
  if (ws_size < WS_NEED) return;

  bf16* A0  = (bf16*)(ws + OFF_A0);
  bf16* Wt0 = (bf16*)(ws + OFF_W0);
  bf16* W1r = (bf16*)(ws + OFF_W1R);
  bf16* W2r = (bf16*)(ws + OFF_W2R);
  bf16* W01 = (bf16*)(ws + OFF_W01);
  bf16* W12 = (bf16*)(ws + OFF_W12);
  bf16* WtO = (bf16*)(ws + OFF_WO);
  bf16* Ar1 = (bf16*)(ws + OFF_AR1);
  bf16* Ar2 = (bf16*)(ws + OFF_AR2);
  bf16* Ah0 = (bf16*)(ws + OFF_AH0);
  bf16* Ah1 = Ar1;   // h1_in bf16 dead after D1
  bf16* Ah2 = Ar2;   // h2_in bf16 dead after D1
  // split-K partials in regions dead after D1 (A0/Wt0/W1r/W2r): 32 MB used,
  // ends at 33.6 MB < OFF_W01 (37.7 MB) -> W01/W12 untouched.
  float* P0 = (float*)(ws + 0);
  float* P1 = (float*)(ws + 16777216);

  float* o_h0  = out;
  float* o_h1  = out + (size_t)BB * NN;
  float* o_h2  = out + (size_t)2 * BB * NN;
  float* o_out = out + (size_t)3 * BB * NN;

  // --- fused prep (1 dispatch) ---
  PAll pa;
  int n8a = BB * ISZ / 8;
  int n8b = n8a + BB * NN / 8;
  int n8c = n8b + BB * NN / 8;
  int n8d = n8c + BB * NN / 8;
  pa.p[0] = {x,     A0,  ISZ, ISZ + NN, 0,   n8a};
  pa.p[1] = {h0_in, A0,  NN,  ISZ + NN, ISZ, n8b};
  pa.p[2] = {h1_in, Ar1, NN,  NN,       0,   n8c};
  pa.p[3] = {h2_in, Ar2, NN,  NN,       0,   n8d};
  pa.packBlocks = (n8d + 255) / 256;
  int s0 = 0;
  pa.d[0] = {i_to_h0,  nullptr, Wt0, NN,  ISZ + NN, 0,   0, ISZ / 128, s0}; s0 += (ISZ / 128) * (NN / 32);
  pa.d[1] = {h0_w,     nullptr, Wt0, NN,  ISZ + NN, ISZ, 1, NN / 128,  s0}; s0 += (NN / 128) * (NN / 32);
  pa.d[2] = {h1_w,     nullptr, W1r, NN,  NN,       0,   1, NN / 128,  s0}; s0 += (NN / 128) * (NN / 32);
  pa.d[3] = {h2_w,     nullptr, W2r, NN,  NN,       0,   1, NN / 128,  s0}; s0 += (NN / 128) * (NN / 32);
  pa.d[4] = {h0_to_h1, m01,     W01, NN,  NN,       0,   2, NN / 128,  s0}; s0 += (NN / 128) * (NN / 32);
  pa.d[5] = {h1_to_h2, m12,     W12, NN,  NN,       0,   2, NN / 128,  s0}; s0 += (NN / 128) * (NN / 32);
  pa.d[6] = {w_out,    nullptr, WtO, OSZ, NN,       0,   0, NN / 128,  s0}; s0 += (NN / 128) * (OSZ / 32);
  prep_all_k<<<pa.packBlocks + s0, 256, 0, stream>>>(pa);

  // --- D1: S0 (h0) + R1 + R2, 768 blocks of 8 waves, 128x128 K-split body ---
  GP pS0{A0,  Wt0, ISZ + NN, ISZ + NN, ISZ + NN, h0_in, h0_b, nullptr,
         o_h0, NN, Ah0, NN, 0};
  GP pR1{Ar1, W1r, NN, NN, NN, nullptr, nullptr, nullptr, o_h1, NN, nullptr, 0, 1};
  GP pR2{Ar2, W2r, NN, NN, NN, nullptr, nullptr, nullptr, o_h2, NN, nullptr, 0, 1};
  k_tri<<<dim3(NN / 128, BB / 128, 3), 512, 0, stream>>>(pS0, pR1, pR2);

  // --- D2: F1 = h0@W01 split-K=2 (512 blocks); combine with R1 -> h1 ---
  GP pG1a{Ah0,          W01,          NN / 2, NN, NN, nullptr, nullptr, nullptr, P0, NN, nullptr, 0, 1};
  GP pG1b{Ah0 + NN / 2, W01 + NN / 2, NN / 2, NN, NN, nullptr, nullptr, nullptr, P1, NN, nullptr, 0, 1};
  k_split<<<dim3(NN / 128, BB / 128, 2), 512, 0, stream>>>(pG1a, pG1b);
  k_epi<<<BB * NN / 2048, 256, 0, stream>>>(P0, P1, o_h1, h1_in, h1_b, o_h1, Ah1);

  // --- D3: F2 = h1@W12 split-K=2; combine with R2 -> h2 ---
  GP pG2a{Ah1,          W12,          NN / 2, NN, NN, nullptr, nullptr, nullptr, P0, NN, nullptr, 0, 1};
  GP pG2b{Ah1 + NN / 2, W12 + NN / 2, NN / 2, NN, NN, nullptr, nullptr, nullptr, P1, NN, nullptr, 0, 1};
  k_split<<<dim3(NN / 128, BB / 128, 2), 512, 0, stream>>>(pG2a, pG2b);
  k_epi<<<BB * NN / 2048, 256, 0, stream>>>(P0, P1, o_h2, h2_in, h2_b, o_h2, Ah2);

  // --- D4: out = h2 @ w_out ---
  GP pO{Ah2, WtO, NN, NN, NN, nullptr, nullptr, nullptr, o_out, OSZ, nullptr, 0, 1};
  k_out<<<dim3(OSZ / 64, BB / 32), 512, 0, stream>>>(pO);
}